// Round 1
// baseline (1990.968 us; speedup 1.0000x reference)
//
#include <hip/hip_runtime.h>
#include <math.h>

#define NB 2
#define SEQ 3073
#define DIM 768
#define NH 12
#define DH 64
#define TD 2304
#define HHH 64
#define WWW 48
#define NPATCH 3072
#define QSCALE 0.125f

#define BHN (NB * NH)          // 24
#define MROWS (NB * SEQ)       // 6146
#define QKV_CNT (NB * NH * SEQ * DH)  // 4720128

// ---------------------------------------------------------------------------
// Kernel 1: qkv = x @ qkv_w^T (NT gemm), scatter into q/k/v [B][H][N][DH].
// Q is pre-scaled by DH^-0.5.
// ---------------------------------------------------------------------------
__global__ __launch_bounds__(256) void qkv_gemm(const float* __restrict__ x,
                                                const float* __restrict__ w,
                                                float* __restrict__ qkv) {
    __shared__ float Xs[64][33];
    __shared__ float Ws[64][33];
    const int tid = threadIdx.x;
    const int tx = tid & 15, ty = tid >> 4;
    const int m0 = blockIdx.x * 64;
    const int n0 = blockIdx.y * 64;

    float acc[4][4] = {};

    for (int k0 = 0; k0 < DIM; k0 += 32) {
        #pragma unroll
        for (int i = 0; i < 8; ++i) {
            int flat = tid + 256 * i;
            int r = flat >> 5, c = flat & 31;
            int gm = m0 + r;
            Xs[r][c] = (gm < MROWS) ? x[gm * DIM + k0 + c] : 0.f;
            int gn = n0 + r;   // always < TD (grid exact)
            Ws[r][c] = w[gn * DIM + k0 + c];
        }
        __syncthreads();
        #pragma unroll 8
        for (int kk = 0; kk < 32; ++kk) {
            float a[4], b[4];
            #pragma unroll
            for (int i = 0; i < 4; ++i) a[i] = Xs[ty * 4 + i][kk];
            #pragma unroll
            for (int j = 0; j < 4; ++j) b[j] = Ws[tx * 4 + j][kk];
            #pragma unroll
            for (int i = 0; i < 4; ++i)
                #pragma unroll
                for (int j = 0; j < 4; ++j)
                    acc[i][j] = fmaf(a[i], b[j], acc[i][j]);
        }
        __syncthreads();
    }

    #pragma unroll
    for (int i = 0; i < 4; ++i) {
        int gm = m0 + ty * 4 + i;
        if (gm >= MROWS) continue;
        int b = gm / SEQ;
        int row = gm - b * SEQ;
        #pragma unroll
        for (int j = 0; j < 4; ++j) {
            int gn = n0 + tx * 4 + j;
            int which = gn / DIM;
            int rr = gn - which * DIM;
            int h = rr >> 6;
            int dd = rr & 63;
            float v = acc[i][j];
            if (which == 0) v *= QSCALE;
            qkv[(size_t)which * QKV_CNT +
                ((size_t)((b * NH + h) * SEQ) + row) * DH + dd] = v;
        }
    }
}

// ---------------------------------------------------------------------------
// Kernel 2: flash attention, fp32. One block = 64 q-rows of one (b,h).
// K LDS buffer is reused for P (saves 16.6 KB -> 3 blocks/CU).
// ---------------------------------------------------------------------------
__global__ __launch_bounds__(256) void attn_kernel(const float* __restrict__ q,
                                                   const float* __restrict__ k,
                                                   const float* __restrict__ v,
                                                   float* __restrict__ att) {
    __shared__ float Qs[64][65];
    __shared__ float KP[64][65];   // K tile, later reused for P tile
    __shared__ float Vs[64][64];

    const int tid = threadIdx.x;
    const int tx = tid & 15, ty = tid >> 4;
    const int bh = blockIdx.y;
    const int b = bh / NH;
    const int h = bh - b * NH;
    const int q0 = blockIdx.x * 64;

    const float* qb = q + (size_t)bh * SEQ * DH;
    const float* kb = k + (size_t)bh * SEQ * DH;
    const float* vb = v + (size_t)bh * SEQ * DH;

    // stage Q tile (stays resident)
    #pragma unroll
    for (int i = 0; i < 16; ++i) {
        int flat = tid + 256 * i;
        int r = flat >> 6, c = flat & 63;
        int gr = q0 + r;
        Qs[r][c] = (gr < SEQ) ? qb[gr * DH + c] : 0.f;
    }

    float o[4][4] = {};
    float mi[4] = {-1e30f, -1e30f, -1e30f, -1e30f};
    float li[4] = {};

    for (int k0 = 0; k0 < SEQ; k0 += 64) {
        __syncthreads();   // previous iteration done with KP/Vs (also covers Qs staging)
        #pragma unroll
        for (int i = 0; i < 16; ++i) {
            int flat = tid + 256 * i;
            int r = flat >> 6, c = flat & 63;
            int gr = k0 + r;
            float kv = (gr < SEQ) ? kb[gr * DH + c] : 0.f;
            float vv = (gr < SEQ) ? vb[gr * DH + c] : 0.f;
            KP[r][c] = kv;
            Vs[r][c] = vv;
        }
        __syncthreads();

        // S = Q (pre-scaled) . K^T   — 64x64 tile, 4x4 per thread
        float s[4][4] = {};
        #pragma unroll 8
        for (int kk = 0; kk < 64; ++kk) {
            float a[4], bb[4];
            #pragma unroll
            for (int i = 0; i < 4; ++i) a[i] = Qs[ty * 4 + i][kk];
            #pragma unroll
            for (int j = 0; j < 4; ++j) bb[j] = KP[tx * 4 + j][kk];
            #pragma unroll
            for (int i = 0; i < 4; ++i)
                #pragma unroll
                for (int j = 0; j < 4; ++j)
                    s[i][j] = fmaf(a[i], bb[j], s[i][j]);
        }
        // mask out-of-range key columns
        #pragma unroll
        for (int j = 0; j < 4; ++j) {
            if (k0 + tx * 4 + j >= SEQ) {
                #pragma unroll
                for (int i = 0; i < 4; ++i) s[i][j] = -1e30f;
            }
        }

        // online softmax per q-row (row lives in a 16-lane shuffle group)
        float p[4][4];
        float al[4];
        #pragma unroll
        for (int i = 0; i < 4; ++i) {
            float rm = fmaxf(fmaxf(s[i][0], s[i][1]), fmaxf(s[i][2], s[i][3]));
            #pragma unroll
            for (int off = 1; off < 16; off <<= 1)
                rm = fmaxf(rm, __shfl_xor(rm, off, 16));
            float mn = fmaxf(mi[i], rm);
            al[i] = __expf(mi[i] - mn);
            mi[i] = mn;
            float rs = 0.f;
            #pragma unroll
            for (int j = 0; j < 4; ++j) {
                p[i][j] = __expf(s[i][j] - mn);
                rs += p[i][j];
            }
            #pragma unroll
            for (int off = 1; off < 16; off <<= 1)
                rs += __shfl_xor(rs, off, 16);
            li[i] = li[i] * al[i] + rs;
        }

        __syncthreads();   // everyone done reading KP as K
        #pragma unroll
        for (int i = 0; i < 4; ++i)
            #pragma unroll
            for (int j = 0; j < 4; ++j)
                KP[ty * 4 + i][tx * 4 + j] = p[i][j];
        __syncthreads();

        // rescale accumulators, then O += P.V
        #pragma unroll
        for (int i = 0; i < 4; ++i)
            #pragma unroll
            for (int j = 0; j < 4; ++j)
                o[i][j] *= al[i];

        #pragma unroll 8
        for (int kc = 0; kc < 64; ++kc) {
            float pa[4], vv[4];
            #pragma unroll
            for (int i = 0; i < 4; ++i) pa[i] = KP[ty * 4 + i][kc];
            #pragma unroll
            for (int j = 0; j < 4; ++j) vv[j] = Vs[kc][tx * 4 + j];
            #pragma unroll
            for (int i = 0; i < 4; ++i)
                #pragma unroll
                for (int j = 0; j < 4; ++j)
                    o[i][j] = fmaf(pa[i], vv[j], o[i][j]);
        }
    }

    // store: att[b][row][h*64 + d]
    #pragma unroll
    for (int i = 0; i < 4; ++i) {
        int gr = q0 + ty * 4 + i;
        if (gr >= SEQ) continue;
        float inv = 1.f / li[i];
        #pragma unroll
        for (int j = 0; j < 4; ++j)
            att[((size_t)(b * SEQ + gr)) * DIM + h * DH + tx * 4 + j] =
                o[i][j] * inv;
    }
}

// ---------------------------------------------------------------------------
// Kernel 3: depthwise 3x3 conv on V (spatial 64x48 per (b,h)), add into att.
// Token 0 (cls) gets no positional embedding.
// ---------------------------------------------------------------------------
__global__ __launch_bounds__(256) void conv_pe(const float* __restrict__ v,
                                               const float* __restrict__ cw,
                                               const float* __restrict__ cb,
                                               float* __restrict__ att) {
    const int tid = threadIdx.x;
    const int c = tid & 63;
    const int tl = tid >> 6;
    const int blk = blockIdx.x;          // bh * 768 + pb
    const int bh = blk / 768;
    const int pb = blk - bh * 768;
    const int p = pb * 4 + tl;           // patch index within (b,h)
    const int y = p / WWW;
    const int x0 = p - y * WWW;

    const float* vb = v + (size_t)bh * SEQ * DH;
    float acc = cb[c];
    #pragma unroll
    for (int dy = -1; dy <= 1; ++dy) {
        int yy = y + dy;
        if (yy < 0 || yy >= HHH) continue;
        #pragma unroll
        for (int dx = -1; dx <= 1; ++dx) {
            int xx = x0 + dx;
            if (xx < 0 || xx >= WWW) continue;
            acc = fmaf(vb[(size_t)(1 + yy * WWW + xx) * DH + c],
                       cw[c * 9 + (dy + 1) * 3 + (dx + 1)], acc);
        }
    }
    const int b = bh / NH;
    const int h = bh - b * NH;
    att[((size_t)(b * SEQ + 1 + p)) * DIM + h * DH + c] += acc;
}

// ---------------------------------------------------------------------------
// Kernel 4: out = att @ proj_w^T + proj_b
// ---------------------------------------------------------------------------
__global__ __launch_bounds__(256) void proj_gemm(const float* __restrict__ a,
                                                 const float* __restrict__ w,
                                                 const float* __restrict__ bias,
                                                 float* __restrict__ out) {
    __shared__ float As[64][33];
    __shared__ float Ws[64][33];
    const int tid = threadIdx.x;
    const int tx = tid & 15, ty = tid >> 4;
    const int m0 = blockIdx.x * 64;
    const int n0 = blockIdx.y * 64;

    float acc[4][4] = {};

    for (int k0 = 0; k0 < DIM; k0 += 32) {
        #pragma unroll
        for (int i = 0; i < 8; ++i) {
            int flat = tid + 256 * i;
            int r = flat >> 5, c = flat & 31;
            int gm = m0 + r;
            As[r][c] = (gm < MROWS) ? a[gm * DIM + k0 + c] : 0.f;
            int gn = n0 + r;   // always < DIM (grid exact)
            Ws[r][c] = w[gn * DIM + k0 + c];
        }
        __syncthreads();
        #pragma unroll 8
        for (int kk = 0; kk < 32; ++kk) {
            float av[4], bv[4];
            #pragma unroll
            for (int i = 0; i < 4; ++i) av[i] = As[ty * 4 + i][kk];
            #pragma unroll
            for (int j = 0; j < 4; ++j) bv[j] = Ws[tx * 4 + j][kk];
            #pragma unroll
            for (int i = 0; i < 4; ++i)
                #pragma unroll
                for (int j = 0; j < 4; ++j)
                    acc[i][j] = fmaf(av[i], bv[j], acc[i][j]);
        }
        __syncthreads();
    }

    #pragma unroll
    for (int i = 0; i < 4; ++i) {
        int gm = m0 + ty * 4 + i;
        if (gm >= MROWS) continue;
        #pragma unroll
        for (int j = 0; j < 4; ++j) {
            int gn = n0 + tx * 4 + j;
            out[(size_t)gm * DIM + gn] = acc[i][j] + bias[gn];
        }
    }
}

// ---------------------------------------------------------------------------
extern "C" void kernel_launch(void* const* d_in, const int* in_sizes, int n_in,
                              void* d_out, int out_size, void* d_ws, size_t ws_size,
                              hipStream_t stream) {
    const float* x      = (const float*)d_in[0];
    const float* qkv_w  = (const float*)d_in[1];
    const float* proj_w = (const float*)d_in[2];
    const float* proj_b = (const float*)d_in[3];
    const float* conv_w = (const float*)d_in[4];
    const float* conv_b = (const float*)d_in[5];
    float* out = (float*)d_out;

    float* ws  = (float*)d_ws;
    float* q   = ws;                   // [B][H][N][DH]
    float* k   = q + QKV_CNT;
    float* v   = k + QKV_CNT;
    float* att = v + QKV_CNT;          // [B][N][DIM]

    // 1. QKV projection + scatter
    qkv_gemm<<<dim3(97, 36), 256, 0, stream>>>(x, qkv_w, q);
    // 2. flash attention -> att (layout [B][N][H*DH])
    attn_kernel<<<dim3(49, BHN), 256, 0, stream>>>(q, k, v, att);
    // 3. depthwise conv positional embedding, accumulated into att
    conv_pe<<<BHN * (NPATCH / 4), 256, 0, stream>>>(v, conv_w, conv_b, att);
    // 4. output projection
    proj_gemm<<<dim3(97, 12), 256, 0, stream>>>(att, proj_w, proj_b, out);
}

// Round 2
// 952.869 us; speedup vs baseline: 2.0894x; 2.0894x over previous
//
#include <hip/hip_runtime.h>
#include <math.h>

#define NB 2
#define SEQ 3073
#define DIM 768
#define NH 12
#define DH 64
#define HHH 64
#define WWW 48
#define NPATCH 3072
#define QSCALE 0.125f

#define BHN (NB * NH)                 // 24
#define MROWS (NB * SEQ)              // 6146
#define CNT (BHN * SEQ * DH)          // 4720128 elements per qkv buffer
#define VTSTRIDE 3136                 // padded kc stride for Vt (16B-aligned rows)

typedef __attribute__((ext_vector_type(8))) short s8v;   // 8 x bf16 bits
typedef __attribute__((ext_vector_type(4))) float f4v;   // MFMA accumulator

#define MFMA16(a, b, c) __builtin_amdgcn_mfma_f32_16x16x32_bf16((a), (b), (c), 0, 0, 0)

__device__ __forceinline__ ushort f2bf(float f) {   // RTNE float -> bf16 bits
    unsigned x = __float_as_uint(f);
    return (ushort)((x + 0x7FFFu + ((x >> 16) & 1u)) >> 16);
}
__device__ __forceinline__ float bf2f(ushort u) {
    return __uint_as_float(((unsigned)u) << 16);
}

// ---------------------------------------------------------------------------
// Kernel 1: qkv = x @ qkv_w^T (fp32 NT gemm). Epilogue splits:
//   Q -> (q_hi + q_lo) bf16 pair (pre-scaled), K -> (k_hi + k_lo), V -> bf16.
// ---------------------------------------------------------------------------
__global__ __launch_bounds__(256) void qkv_gemm(const float* __restrict__ x,
                                                const float* __restrict__ w,
                                                ushort* __restrict__ q_hi,
                                                ushort* __restrict__ q_lo,
                                                ushort* __restrict__ k_hi,
                                                ushort* __restrict__ k_lo,
                                                ushort* __restrict__ v_bf) {
    __shared__ float Xs[64][33];
    __shared__ float Ws[64][33];
    const int tid = threadIdx.x;
    const int tx = tid & 15, ty = tid >> 4;
    const int m0 = blockIdx.x * 64;
    const int n0 = blockIdx.y * 64;

    float acc[4][4] = {};

    for (int k0 = 0; k0 < DIM; k0 += 32) {
        #pragma unroll
        for (int i = 0; i < 8; ++i) {
            int flat = tid + 256 * i;
            int r = flat >> 5, c = flat & 31;
            int gm = m0 + r;
            Xs[r][c] = (gm < MROWS) ? x[gm * DIM + k0 + c] : 0.f;
            int gn = n0 + r;
            Ws[r][c] = w[gn * DIM + k0 + c];
        }
        __syncthreads();
        #pragma unroll 8
        for (int kk = 0; kk < 32; ++kk) {
            float a[4], b[4];
            #pragma unroll
            for (int i = 0; i < 4; ++i) a[i] = Xs[ty * 4 + i][kk];
            #pragma unroll
            for (int j = 0; j < 4; ++j) b[j] = Ws[tx * 4 + j][kk];
            #pragma unroll
            for (int i = 0; i < 4; ++i)
                #pragma unroll
                for (int j = 0; j < 4; ++j)
                    acc[i][j] = fmaf(a[i], b[j], acc[i][j]);
        }
        __syncthreads();
    }

    #pragma unroll
    for (int i = 0; i < 4; ++i) {
        int gm = m0 + ty * 4 + i;
        if (gm >= MROWS) continue;
        int b = gm / SEQ;
        int row = gm - b * SEQ;
        #pragma unroll
        for (int j = 0; j < 4; ++j) {
            int gn = n0 + tx * 4 + j;
            int which = gn / DIM;
            int rr = gn - which * DIM;
            int h = rr >> 6;
            int dd = rr & 63;
            float val = acc[i][j];
            size_t base = ((size_t)(b * NH + h) * SEQ + row) * DH + dd;
            if (which == 0) {
                val *= QSCALE;
                ushort hi = f2bf(val);
                q_hi[base] = hi;
                q_lo[base] = f2bf(val - bf2f(hi));
            } else if (which == 1) {
                ushort hi = f2bf(val);
                k_hi[base] = hi;
                k_lo[base] = f2bf(val - bf2f(hi));
            } else {
                v_bf[base] = f2bf(val);
            }
        }
    }
}

// ---------------------------------------------------------------------------
// Kernel 2: Vt[bh][d][kc] = V[bh][kc][d]  (bf16).  kc >= SEQ zero-filled.
// Reads coalesced; scattered 2B writes coalesce in L2 (each 64B line gets 32).
// ---------------------------------------------------------------------------
__global__ __launch_bounds__(256) void transpose_v(const ushort* __restrict__ v,
                                                   ushort* __restrict__ vt) {
    const int tid = threadIdx.x;
    const int kc0 = blockIdx.x * 64;
    const int bh = blockIdx.y;
    #pragma unroll
    for (int it = 0; it < 2; ++it) {
        int r = (tid >> 3) + it * 32;
        int c0 = (tid & 7) * 8;
        int kc = kc0 + r;
        ushort val[8];
        if (kc < SEQ) {
            *(s8v*)val = *(const s8v*)(v + ((size_t)bh * SEQ + kc) * DH + c0);
        } else {
            #pragma unroll
            for (int j = 0; j < 8; ++j) val[j] = 0;
        }
        #pragma unroll
        for (int j = 0; j < 8; ++j)
            vt[((size_t)bh * DH + c0 + j) * VTSTRIDE + kc] = val[j];
    }
}

// ---------------------------------------------------------------------------
// Kernel 3: MFMA flash attention.
// Block = 64 q-rows of one (b,h); 4 waves x 16-row strips.
// QK^T: bf16 hi/lo (3 passes) -> fp32-accurate scores. PV: bf16.
// LDS tiles XOR-swizzled: byte ^= ((row&7)<<4)  (kills the 128B-stride conflict).
// ---------------------------------------------------------------------------
__device__ __forceinline__ s8v ldsFrag(const ushort* base, int row, int half, int t) {
    int byte = (row * 128 + half * 64 + t * 16) ^ ((row & 7) << 4);
    return *(const s8v*)((const char*)base + byte);
}

__global__ __launch_bounds__(256) void attn_mfma(const ushort* __restrict__ qh,
                                                 const ushort* __restrict__ ql,
                                                 const ushort* __restrict__ kh,
                                                 const ushort* __restrict__ kl,
                                                 const ushort* __restrict__ vt,
                                                 float* __restrict__ att) {
    __shared__ ushort Kh[4096];      // 64 x 64 bf16, swizzled
    __shared__ ushort Kl[4096];
    __shared__ ushort Vt[4096];      // [d][kc], swizzled
    __shared__ ushort Pl[4][1024];   // per-wave 16 x 64 bf16, swizzled

    const int tid = threadIdx.x;
    const int w = tid >> 6;
    const int lane = tid & 63;
    const int lo = lane & 15;
    const int t = lane >> 4;
    const int bh = blockIdx.y;
    const int q0 = blockIdx.x * 64;

    // Q fragments, resident in registers. A-frag: row = lane&15, k = half*32+t*8+e.
    int qr = q0 + w * 16 + lo;
    if (qr > SEQ - 1) qr = SEQ - 1;
    const size_t qoff = ((size_t)bh * SEQ + qr) * DH + t * 8;
    s8v qfh0 = *(const s8v*)(qh + qoff);
    s8v qfh1 = *(const s8v*)(qh + qoff + 32);
    s8v qfl0 = *(const s8v*)(ql + qoff);
    s8v qfl1 = *(const s8v*)(ql + qoff + 32);

    f4v o[4] = {};                       // o[dt][reg] : d = dt*16+lo, row = t*4+reg
    float mi[4] = {-1e30f, -1e30f, -1e30f, -1e30f};
    float li[4] = {0.f, 0.f, 0.f, 0.f};

    for (int k0 = 0; k0 < SEQ; k0 += 64) {
        __syncthreads();   // all waves done reading Kh/Kl/Vt from prev iter

        // stage K_hi, K_lo (row-major [kc][d]) and Vt ([d][kc]) with XOR swizzle
        {
            const ushort* gk_h = kh + ((size_t)bh * SEQ + k0) * DH;
            const ushort* gk_l = kl + ((size_t)bh * SEQ + k0) * DH;
            const ushort* gv = vt + (size_t)bh * DH * VTSTRIDE + k0;
            #pragma unroll
            for (int iss = 0; iss < 2; ++iss) {
                int slot = tid + 256 * iss;      // 0..511
                int r = slot >> 3;               // tile row 0..63
                int cu = (slot & 7) * 8;         // ushort col
                int byte = (r * 128 + cu * 2) ^ ((r & 7) << 4);
                s8v a = *(const s8v*)(gk_h + (size_t)r * DH + cu);
                s8v b = *(const s8v*)(gk_l + (size_t)r * DH + cu);
                s8v c = *(const s8v*)(gv + (size_t)r * VTSTRIDE + cu);
                *(s8v*)((char*)Kh + byte) = a;
                *(s8v*)((char*)Kl + byte) = b;
                *(s8v*)((char*)Vt + byte) = c;
            }
        }
        __syncthreads();

        // S = Q . K^T  (hi/lo 3-pass, fp32 accum). sv[tc][reg]: col = k0+tc*16+lo
        f4v sv[4];
        #pragma unroll
        for (int tc = 0; tc < 4; ++tc) {
            int row = tc * 16 + lo;
            s8v bh0 = ldsFrag(Kh, row, 0, t);
            s8v bh1 = ldsFrag(Kh, row, 1, t);
            s8v bl0 = ldsFrag(Kl, row, 0, t);
            s8v bl1 = ldsFrag(Kl, row, 1, t);
            f4v a = {0.f, 0.f, 0.f, 0.f};
            a = MFMA16(qfl0, bh0, a);
            a = MFMA16(qfl1, bh1, a);
            a = MFMA16(qfh0, bl0, a);
            a = MFMA16(qfh1, bl1, a);
            a = MFMA16(qfh0, bh0, a);
            a = MFMA16(qfh1, bh1, a);
            sv[tc] = a;
        }
        // mask invalid key columns
        #pragma unroll
        for (int tc = 0; tc < 4; ++tc)
            if (k0 + tc * 16 + lo >= SEQ)
                sv[tc] = (f4v){-1e30f, -1e30f, -1e30f, -1e30f};

        // online softmax per q-row; P written to per-wave LDS as bf16
        float al[4];
        #pragma unroll
        for (int r = 0; r < 4; ++r) {
            float rm = fmaxf(fmaxf(sv[0][r], sv[1][r]), fmaxf(sv[2][r], sv[3][r]));
            #pragma unroll
            for (int off = 1; off < 16; off <<= 1)
                rm = fmaxf(rm, __shfl_xor(rm, off, 16));
            float mn = fmaxf(mi[r], rm);
            al[r] = __expf(mi[r] - mn);
            mi[r] = mn;
            int prow = t * 4 + r;
            float rs = 0.f;
            #pragma unroll
            for (int tc = 0; tc < 4; ++tc) {
                float p = __expf(sv[tc][r] - mn);
                rs += p;
                int byte = (prow * 128 + (tc * 16 + lo) * 2) ^ ((prow & 7) << 4);
                *(ushort*)((char*)Pl[w] + byte) = f2bf(p);
            }
            #pragma unroll
            for (int off = 1; off < 16; off <<= 1)
                rs += __shfl_xor(rs, off, 16);
            li[r] = li[r] * al[r] + rs;
        }

        // O = O*al + P.V   (P from own-wave LDS; Vt gives contiguous B-frags)
        s8v pf0 = ldsFrag(Pl[w], lo, 0, t);
        s8v pf1 = ldsFrag(Pl[w], lo, 1, t);
        #pragma unroll
        for (int dt = 0; dt < 4; ++dt) {
            #pragma unroll
            for (int r = 0; r < 4; ++r) o[dt][r] *= al[r];
        }
        #pragma unroll
        for (int dt = 0; dt < 4; ++dt) {
            s8v v0 = ldsFrag(Vt, dt * 16 + lo, 0, t);
            s8v v1 = ldsFrag(Vt, dt * 16 + lo, 1, t);
            o[dt] = MFMA16(pf0, v0, o[dt]);
            o[dt] = MFMA16(pf1, v1, o[dt]);
        }
    }

    // epilogue: att[b][row][h*64 + d] = o / li
    const int b = bh / NH;
    const int h = bh - b * NH;
    #pragma unroll
    for (int r = 0; r < 4; ++r) {
        int row = q0 + w * 16 + t * 4 + r;
        if (row >= SEQ) continue;
        float inv = 1.f / li[r];
        #pragma unroll
        for (int dt = 0; dt < 4; ++dt)
            att[((size_t)(b * SEQ + row)) * DIM + h * DH + dt * 16 + lo] =
                o[dt][r] * inv;
    }
}

// ---------------------------------------------------------------------------
// Kernel 4: depthwise 3x3 conv on V (bf16 in, fp32 math), add into att.
// ---------------------------------------------------------------------------
__global__ __launch_bounds__(256) void conv_pe(const ushort* __restrict__ v,
                                               const float* __restrict__ cw,
                                               const float* __restrict__ cb,
                                               float* __restrict__ att) {
    const int tid = threadIdx.x;
    const int c = tid & 63;
    const int tl = tid >> 6;
    const int blk = blockIdx.x;
    const int bh = blk / 768;
    const int pb = blk - bh * 768;
    const int p = pb * 4 + tl;
    const int y = p / WWW;
    const int x0 = p - y * WWW;

    const ushort* vb = v + (size_t)bh * SEQ * DH;
    float acc = cb[c];
    #pragma unroll
    for (int dy = -1; dy <= 1; ++dy) {
        int yy = y + dy;
        if (yy < 0 || yy >= HHH) continue;
        #pragma unroll
        for (int dx = -1; dx <= 1; ++dx) {
            int xx = x0 + dx;
            if (xx < 0 || xx >= WWW) continue;
            acc = fmaf(bf2f(vb[(size_t)(1 + yy * WWW + xx) * DH + c]),
                       cw[c * 9 + (dy + 1) * 3 + (dx + 1)], acc);
        }
    }
    const int b = bh / NH;
    const int h = bh - b * NH;
    att[((size_t)(b * SEQ + 1 + p)) * DIM + h * DH + c] += acc;
}

// ---------------------------------------------------------------------------
// Kernel 5: out = att @ proj_w^T + proj_b   (fp32)
// ---------------------------------------------------------------------------
__global__ __launch_bounds__(256) void proj_gemm(const float* __restrict__ a,
                                                 const float* __restrict__ w,
                                                 const float* __restrict__ bias,
                                                 float* __restrict__ out) {
    __shared__ float As[64][33];
    __shared__ float Ws[64][33];
    const int tid = threadIdx.x;
    const int tx = tid & 15, ty = tid >> 4;
    const int m0 = blockIdx.x * 64;
    const int n0 = blockIdx.y * 64;

    float acc[4][4] = {};

    for (int k0 = 0; k0 < DIM; k0 += 32) {
        #pragma unroll
        for (int i = 0; i < 8; ++i) {
            int flat = tid + 256 * i;
            int r = flat >> 5, c = flat & 31;
            int gm = m0 + r;
            As[r][c] = (gm < MROWS) ? a[gm * DIM + k0 + c] : 0.f;
            int gn = n0 + r;
            Ws[r][c] = w[gn * DIM + k0 + c];
        }
        __syncthreads();
        #pragma unroll 8
        for (int kk = 0; kk < 32; ++kk) {
            float av[4], bv[4];
            #pragma unroll
            for (int i = 0; i < 4; ++i) av[i] = As[ty * 4 + i][kk];
            #pragma unroll
            for (int j = 0; j < 4; ++j) bv[j] = Ws[tx * 4 + j][kk];
            #pragma unroll
            for (int i = 0; i < 4; ++i)
                #pragma unroll
                for (int j = 0; j < 4; ++j)
                    acc[i][j] = fmaf(av[i], bv[j], acc[i][j]);
        }
        __syncthreads();
    }

    #pragma unroll
    for (int i = 0; i < 4; ++i) {
        int gm = m0 + ty * 4 + i;
        if (gm >= MROWS) continue;
        #pragma unroll
        for (int j = 0; j < 4; ++j) {
            int gn = n0 + tx * 4 + j;
            out[(size_t)gm * DIM + gn] = acc[i][j] + bias[gn];
        }
    }
}

// ---------------------------------------------------------------------------
extern "C" void kernel_launch(void* const* d_in, const int* in_sizes, int n_in,
                              void* d_out, int out_size, void* d_ws, size_t ws_size,
                              hipStream_t stream) {
    const float* x      = (const float*)d_in[0];
    const float* qkv_w  = (const float*)d_in[1];
    const float* proj_w = (const float*)d_in[2];
    const float* proj_b = (const float*)d_in[3];
    const float* conv_w = (const float*)d_in[4];
    const float* conv_b = (const float*)d_in[5];
    float* out = (float*)d_out;

    ushort* q_hi = (ushort*)d_ws;
    ushort* q_lo = q_hi + CNT;
    ushort* k_hi = q_lo + CNT;
    ushort* k_lo = k_hi + CNT;
    ushort* v_bf = k_lo + CNT;            // K-staging tail over-reads land here (in-ws, safe)
    ushort* vtb  = v_bf + CNT;            // [bh][64][VTSTRIDE]
    float*  att  = (float*)(vtb + (size_t)BHN * DH * VTSTRIDE);

    qkv_gemm<<<dim3(97, 36), 256, 0, stream>>>(x, qkv_w, q_hi, q_lo, k_hi, k_lo, v_bf);
    transpose_v<<<dim3(49, BHN), 256, 0, stream>>>(v_bf, vtb);
    attn_mfma<<<dim3(49, BHN), 256, 0, stream>>>(q_hi, q_lo, k_hi, k_lo, vtb, att);
    conv_pe<<<BHN * (NPATCH / 4), 256, 0, stream>>>(v_bf, conv_w, conv_b, att);
    proj_gemm<<<dim3(97, 12), 256, 0, stream>>>(att, proj_w, proj_b, out);
}

// Round 3
// 454.016 us; speedup vs baseline: 4.3852x; 2.0988x over previous
//
#include <hip/hip_runtime.h>
#include <math.h>

#define NB 2
#define SEQ 3073
#define DIM 768
#define NH 12
#define DH 64
#define HHH 64
#define WWW 48
#define NPATCH 3072
#define QSCALE 0.125f

#define BHN (NB * NH)                 // 24
#define MROWS (NB * SEQ)              // 6146
#define MPAD 6272                     // 49 * 128
#define CNT (BHN * SEQ * DH)          // 4720128
#define VTSTRIDE 3136

typedef __attribute__((ext_vector_type(8))) short s8v;    // 8 x bf16 bits
typedef __attribute__((ext_vector_type(4))) float f4v;    // MFMA accumulator
typedef __attribute__((ext_vector_type(4))) ushort u4v;   // 4 x bf16 bits

#define MFMA16(a, b, c) __builtin_amdgcn_mfma_f32_16x16x32_bf16((a), (b), (c), 0, 0, 0)

__device__ __forceinline__ ushort f2bf(float f) {   // RTNE float -> bf16 bits
    unsigned x = __float_as_uint(f);
    return (ushort)((x + 0x7FFFu + ((x >> 16) & 1u)) >> 16);
}
__device__ __forceinline__ float bf2f(ushort u) {
    return __uint_as_float(((unsigned)u) << 16);
}

// swizzled LDS fragment read: [row][64] bf16 tile, byte ^= ((row&7)<<4)
__device__ __forceinline__ s8v ldsFrag(const ushort* base, int row, int half, int t) {
    int byte = (row * 128 + half * 64 + t * 16) ^ ((row & 7) << 4);
    return *(const s8v*)((const char*)base + byte);
}

// ---------------------------------------------------------------------------
// split_hilo: fp32 -> bf16 (hi, lo) pair; zero-pads [n_in, 4*n_grp).
// ---------------------------------------------------------------------------
__global__ __launch_bounds__(256) void split_hilo(const float* __restrict__ in,
                                                  ushort* __restrict__ hi,
                                                  ushort* __restrict__ lo,
                                                  int n_in, int n_grp) {
    for (int g = blockIdx.x * 256 + threadIdx.x; g < n_grp; g += gridDim.x * 256) {
        int i0 = g * 4;
        float4 vv;
        if (i0 + 4 <= n_in) {
            vv = *(const float4*)(in + i0);
        } else {
            vv.x = (i0 + 0 < n_in) ? in[i0 + 0] : 0.f;
            vv.y = (i0 + 1 < n_in) ? in[i0 + 1] : 0.f;
            vv.z = (i0 + 2 < n_in) ? in[i0 + 2] : 0.f;
            vv.w = (i0 + 3 < n_in) ? in[i0 + 3] : 0.f;
        }
        float v[4] = {vv.x, vv.y, vv.z, vv.w};
        u4v hv, lv;
        #pragma unroll
        for (int j = 0; j < 4; ++j) {
            ushort hb = f2bf(v[j]);
            hv[j] = hb;
            lv[j] = f2bf(v[j] - bf2f(hb));
        }
        *(u4v*)(hi + i0) = hv;
        *(u4v*)(lo + i0) = lv;
    }
}

// ---------------------------------------------------------------------------
// Shared MFMA tile core: C[128x128] = A[128xK] . B[128xK]^T, K=768, hi/lo
// 3-pass bf16. gA*/gB* already offset to the tile's first row. acc[4][4]
// per wave; wave w -> quadrant (wr = w>>1, wc = w&1).
// ---------------------------------------------------------------------------
__device__ __forceinline__ void mfma_tile_768(const ushort* __restrict__ gAh,
                                              const ushort* __restrict__ gAl,
                                              const ushort* __restrict__ gBh,
                                              const ushort* __restrict__ gBl,
                                              ushort* Ah, ushort* Al,
                                              ushort* Bh, ushort* Bl,
                                              f4v acc[4][4]) {
    const int tid = threadIdx.x;
    const int lane = tid & 63;
    const int w = tid >> 6;
    const int lo = lane & 15, t = lane >> 4;
    const int wr = w >> 1, wc = w & 1;

    for (int k0 = 0; k0 < DIM; k0 += 64) {
        __syncthreads();
        #pragma unroll
        for (int i = 0; i < 4; ++i) {
            int s = tid + 256 * i;              // 0..1023 chunk id
            int r = s >> 3, c = s & 7;          // row 0..127, 16B chunk 0..7
            int byte = (r * 128 + c * 16) ^ ((r & 7) << 4);
            size_t go = (size_t)r * DIM + k0 + c * 8;
            s8v a0 = *(const s8v*)(gAh + go);
            s8v a1 = *(const s8v*)(gAl + go);
            s8v b0 = *(const s8v*)(gBh + go);
            s8v b1 = *(const s8v*)(gBl + go);
            *(s8v*)((char*)Ah + byte) = a0;
            *(s8v*)((char*)Al + byte) = a1;
            *(s8v*)((char*)Bh + byte) = b0;
            *(s8v*)((char*)Bl + byte) = b1;
        }
        __syncthreads();

        #pragma unroll
        for (int h = 0; h < 2; ++h) {
            s8v af_h[4], af_l[4];
            #pragma unroll
            for (int i = 0; i < 4; ++i) {
                int row = wr * 64 + i * 16 + lo;
                af_h[i] = ldsFrag(Ah, row, h, t);
                af_l[i] = ldsFrag(Al, row, h, t);
            }
            #pragma unroll
            for (int j = 0; j < 4; ++j) {
                int row = wc * 64 + j * 16 + lo;
                s8v bf_h = ldsFrag(Bh, row, h, t);
                s8v bf_l = ldsFrag(Bl, row, h, t);
                #pragma unroll
                for (int i = 0; i < 4; ++i) {
                    acc[i][j] = MFMA16(af_h[i], bf_h, acc[i][j]);
                    acc[i][j] = MFMA16(af_h[i], bf_l, acc[i][j]);
                    acc[i][j] = MFMA16(af_l[i], bf_h, acc[i][j]);
                }
            }
        }
    }
}

// ---------------------------------------------------------------------------
// Kernel: QKV projection via MFMA. Epilogue scatters q(hi/lo), k(hi/lo), v.
// ---------------------------------------------------------------------------
__global__ __launch_bounds__(256) void qkv_mfma(const ushort* __restrict__ xh,
                                                const ushort* __restrict__ xl,
                                                const ushort* __restrict__ wh,
                                                const ushort* __restrict__ wl,
                                                ushort* __restrict__ q_hi,
                                                ushort* __restrict__ q_lo,
                                                ushort* __restrict__ k_hi,
                                                ushort* __restrict__ k_lo,
                                                ushort* __restrict__ v_bf) {
    __shared__ ushort Ah[8192], Al[8192], Bh[8192], Bl[8192];   // 64 KB
    const int m0 = blockIdx.x * 128;
    const int nb = blockIdx.y;                  // 0..17
    f4v acc[4][4] = {};
    mfma_tile_768(xh + (size_t)m0 * DIM, xl + (size_t)m0 * DIM,
                  wh + (size_t)nb * 128 * DIM, wl + (size_t)nb * 128 * DIM,
                  Ah, Al, Bh, Bl, acc);

    const int tid = threadIdx.x;
    const int lane = tid & 63;
    const int w = tid >> 6;
    const int lo = lane & 15, t = lane >> 4;
    const int wr = w >> 1, wc = w & 1;
    const int which = nb / 6;                   // 0=q, 1=k, 2=v (uniform)
    const int rr0 = (nb % 6) * 128;

    #pragma unroll
    for (int i = 0; i < 4; ++i) {
        #pragma unroll
        for (int r = 0; r < 4; ++r) {
            int m = m0 + wr * 64 + i * 16 + t * 4 + r;
            if (m >= MROWS) continue;
            int bb = m / SEQ;
            int row = m - bb * SEQ;
            #pragma unroll
            for (int j = 0; j < 4; ++j) {
                int rr = rr0 + wc * 64 + j * 16 + lo;
                int hh = rr >> 6, dd = rr & 63;
                size_t base = ((size_t)(bb * NH + hh) * SEQ + row) * DH + dd;
                float val = acc[i][j][r];
                if (which == 0) {
                    val *= QSCALE;
                    ushort hb = f2bf(val);
                    q_hi[base] = hb;
                    q_lo[base] = f2bf(val - bf2f(hb));
                } else if (which == 1) {
                    ushort hb = f2bf(val);
                    k_hi[base] = hb;
                    k_lo[base] = f2bf(val - bf2f(hb));
                } else {
                    v_bf[base] = f2bf(val);
                }
            }
        }
    }
}

// ---------------------------------------------------------------------------
// Kernel: output projection via MFMA + bias -> out (fp32).
// ---------------------------------------------------------------------------
__global__ __launch_bounds__(256) void proj_mfma(const ushort* __restrict__ ah,
                                                 const ushort* __restrict__ al,
                                                 const ushort* __restrict__ pwh,
                                                 const ushort* __restrict__ pwl,
                                                 const float* __restrict__ bias,
                                                 float* __restrict__ out) {
    __shared__ ushort Ah[8192], Al[8192], Bh[8192], Bl[8192];
    const int m0 = blockIdx.x * 128;
    const int nb = blockIdx.y;                  // 0..5
    f4v acc[4][4] = {};
    mfma_tile_768(ah + (size_t)m0 * DIM, al + (size_t)m0 * DIM,
                  pwh + (size_t)nb * 128 * DIM, pwl + (size_t)nb * 128 * DIM,
                  Ah, Al, Bh, Bl, acc);

    const int tid = threadIdx.x;
    const int lane = tid & 63;
    const int w = tid >> 6;
    const int lo = lane & 15, t = lane >> 4;
    const int wr = w >> 1, wc = w & 1;

    #pragma unroll
    for (int i = 0; i < 4; ++i) {
        #pragma unroll
        for (int r = 0; r < 4; ++r) {
            int m = m0 + wr * 64 + i * 16 + t * 4 + r;
            if (m >= MROWS) continue;
            #pragma unroll
            for (int j = 0; j < 4; ++j) {
                int n = nb * 128 + wc * 64 + j * 16 + lo;
                out[(size_t)m * DIM + n] = acc[i][j][r] + bias[n];
            }
        }
    }
}

// ---------------------------------------------------------------------------
// Vt[bh][d][kc] = V[bh][kc][d]  (bf16), kc >= SEQ zero-filled.
// ---------------------------------------------------------------------------
__global__ __launch_bounds__(256) void transpose_v(const ushort* __restrict__ v,
                                                   ushort* __restrict__ vt) {
    const int tid = threadIdx.x;
    const int kc0 = blockIdx.x * 64;
    const int bh = blockIdx.y;
    #pragma unroll
    for (int it = 0; it < 2; ++it) {
        int r = (tid >> 3) + it * 32;
        int c0 = (tid & 7) * 8;
        int kc = kc0 + r;
        ushort val[8];
        if (kc < SEQ) {
            *(s8v*)val = *(const s8v*)(v + ((size_t)bh * SEQ + kc) * DH + c0);
        } else {
            #pragma unroll
            for (int j = 0; j < 8; ++j) val[j] = 0;
        }
        #pragma unroll
        for (int j = 0; j < 8; ++j)
            vt[((size_t)bh * DH + c0 + j) * VTSTRIDE + kc] = val[j];
    }
}

// ---------------------------------------------------------------------------
// MFMA flash attention (unchanged from R2 — verified).
// ---------------------------------------------------------------------------
__global__ __launch_bounds__(256) void attn_mfma(const ushort* __restrict__ qh,
                                                 const ushort* __restrict__ ql,
                                                 const ushort* __restrict__ kh,
                                                 const ushort* __restrict__ kl,
                                                 const ushort* __restrict__ vt,
                                                 float* __restrict__ att) {
    __shared__ ushort Kh[4096];
    __shared__ ushort Kl[4096];
    __shared__ ushort Vt[4096];
    __shared__ ushort Pl[4][1024];

    const int tid = threadIdx.x;
    const int w = tid >> 6;
    const int lane = tid & 63;
    const int lo = lane & 15;
    const int t = lane >> 4;
    const int bh = blockIdx.y;
    const int q0 = blockIdx.x * 64;

    int qr = q0 + w * 16 + lo;
    if (qr > SEQ - 1) qr = SEQ - 1;
    const size_t qoff = ((size_t)bh * SEQ + qr) * DH + t * 8;
    s8v qfh0 = *(const s8v*)(qh + qoff);
    s8v qfh1 = *(const s8v*)(qh + qoff + 32);
    s8v qfl0 = *(const s8v*)(ql + qoff);
    s8v qfl1 = *(const s8v*)(ql + qoff + 32);

    f4v o[4] = {};
    float mi[4] = {-1e30f, -1e30f, -1e30f, -1e30f};
    float li[4] = {0.f, 0.f, 0.f, 0.f};

    for (int k0 = 0; k0 < SEQ; k0 += 64) {
        __syncthreads();
        {
            const ushort* gk_h = kh + ((size_t)bh * SEQ + k0) * DH;
            const ushort* gk_l = kl + ((size_t)bh * SEQ + k0) * DH;
            const ushort* gv = vt + (size_t)bh * DH * VTSTRIDE + k0;
            #pragma unroll
            for (int iss = 0; iss < 2; ++iss) {
                int slot = tid + 256 * iss;
                int r = slot >> 3;
                int cu = (slot & 7) * 8;
                int byte = (r * 128 + cu * 2) ^ ((r & 7) << 4);
                s8v a = *(const s8v*)(gk_h + (size_t)r * DH + cu);
                s8v b = *(const s8v*)(gk_l + (size_t)r * DH + cu);
                s8v c = *(const s8v*)(gv + (size_t)r * VTSTRIDE + cu);
                *(s8v*)((char*)Kh + byte) = a;
                *(s8v*)((char*)Kl + byte) = b;
                *(s8v*)((char*)Vt + byte) = c;
            }
        }
        __syncthreads();

        f4v sv[4];
        #pragma unroll
        for (int tc = 0; tc < 4; ++tc) {
            int row = tc * 16 + lo;
            s8v bh0 = ldsFrag(Kh, row, 0, t);
            s8v bh1 = ldsFrag(Kh, row, 1, t);
            s8v bl0 = ldsFrag(Kl, row, 0, t);
            s8v bl1 = ldsFrag(Kl, row, 1, t);
            f4v a = {0.f, 0.f, 0.f, 0.f};
            a = MFMA16(qfl0, bh0, a);
            a = MFMA16(qfl1, bh1, a);
            a = MFMA16(qfh0, bl0, a);
            a = MFMA16(qfh1, bl1, a);
            a = MFMA16(qfh0, bh0, a);
            a = MFMA16(qfh1, bh1, a);
            sv[tc] = a;
        }
        #pragma unroll
        for (int tc = 0; tc < 4; ++tc)
            if (k0 + tc * 16 + lo >= SEQ)
                sv[tc] = (f4v){-1e30f, -1e30f, -1e30f, -1e30f};

        float al[4];
        #pragma unroll
        for (int r = 0; r < 4; ++r) {
            float rm = fmaxf(fmaxf(sv[0][r], sv[1][r]), fmaxf(sv[2][r], sv[3][r]));
            #pragma unroll
            for (int off = 1; off < 16; off <<= 1)
                rm = fmaxf(rm, __shfl_xor(rm, off, 16));
            float mn = fmaxf(mi[r], rm);
            al[r] = __expf(mi[r] - mn);
            mi[r] = mn;
            int prow = t * 4 + r;
            float rs = 0.f;
            #pragma unroll
            for (int tc = 0; tc < 4; ++tc) {
                float p = __expf(sv[tc][r] - mn);
                rs += p;
                int byte = (prow * 128 + (tc * 16 + lo) * 2) ^ ((prow & 7) << 4);
                *(ushort*)((char*)Pl[w] + byte) = f2bf(p);
            }
            #pragma unroll
            for (int off = 1; off < 16; off <<= 1)
                rs += __shfl_xor(rs, off, 16);
            li[r] = li[r] * al[r] + rs;
        }

        s8v pf0 = ldsFrag(Pl[w], lo, 0, t);
        s8v pf1 = ldsFrag(Pl[w], lo, 1, t);
        #pragma unroll
        for (int dt = 0; dt < 4; ++dt) {
            #pragma unroll
            for (int r = 0; r < 4; ++r) o[dt][r] *= al[r];
        }
        #pragma unroll
        for (int dt = 0; dt < 4; ++dt) {
            s8v v0 = ldsFrag(Vt, dt * 16 + lo, 0, t);
            s8v v1 = ldsFrag(Vt, dt * 16 + lo, 1, t);
            o[dt] = MFMA16(pf0, v0, o[dt]);
            o[dt] = MFMA16(pf1, v1, o[dt]);
        }
    }

    const int b = bh / NH;
    const int h = bh - b * NH;
    #pragma unroll
    for (int r = 0; r < 4; ++r) {
        int row = q0 + w * 16 + t * 4 + r;
        if (row >= SEQ) continue;
        float inv = 1.f / li[r];
        #pragma unroll
        for (int dt = 0; dt < 4; ++dt)
            att[((size_t)(b * SEQ + row)) * DIM + h * DH + dt * 16 + lo] =
                o[dt][r] * inv;
    }
}

// ---------------------------------------------------------------------------
// Depthwise 3x3 conv positional embedding, added into att.
// ---------------------------------------------------------------------------
__global__ __launch_bounds__(256) void conv_pe(const ushort* __restrict__ v,
                                               const float* __restrict__ cw,
                                               const float* __restrict__ cb,
                                               float* __restrict__ att) {
    const int tid = threadIdx.x;
    const int c = tid & 63;
    const int tl = tid >> 6;
    const int blk = blockIdx.x;
    const int bh = blk / 768;
    const int pb = blk - bh * 768;
    const int p = pb * 4 + tl;
    const int y = p / WWW;
    const int x0 = p - y * WWW;

    const ushort* vb = v + (size_t)bh * SEQ * DH;
    float acc = cb[c];
    #pragma unroll
    for (int dy = -1; dy <= 1; ++dy) {
        int yy = y + dy;
        if (yy < 0 || yy >= HHH) continue;
        #pragma unroll
        for (int dx = -1; dx <= 1; ++dx) {
            int xx = x0 + dx;
            if (xx < 0 || xx >= WWW) continue;
            acc = fmaf(bf2f(vb[(size_t)(1 + yy * WWW + xx) * DH + c]),
                       cw[c * 9 + (dy + 1) * 3 + (dx + 1)], acc);
        }
    }
    const int b = bh / NH;
    const int h = bh - b * NH;
    att[((size_t)(b * SEQ + 1 + p)) * DIM + h * DH + c] += acc;
}

// ---------------------------------------------------------------------------
extern "C" void kernel_launch(void* const* d_in, const int* in_sizes, int n_in,
                              void* d_out, int out_size, void* d_ws, size_t ws_size,
                              hipStream_t stream) {
    const float* x      = (const float*)d_in[0];
    const float* qkv_w  = (const float*)d_in[1];
    const float* proj_w = (const float*)d_in[2];
    const float* proj_b = (const float*)d_in[3];
    const float* conv_w = (const float*)d_in[4];
    const float* conv_b = (const float*)d_in[5];
    float* out = (float*)d_out;

    ushort* ws = (ushort*)d_ws;
    size_t o = 0;
    ushort* xh  = ws + o; o += (size_t)MPAD * DIM;    // 4,816,896
    ushort* xl  = ws + o; o += (size_t)MPAD * DIM;
    ushort* wh  = ws + o; o += (size_t)2304 * DIM;    // 1,769,472
    ushort* wl  = ws + o; o += (size_t)2304 * DIM;
    ushort* pwh = ws + o; o += (size_t)DIM * DIM;     // 589,824
    ushort* pwl = ws + o; o += (size_t)DIM * DIM;
    ushort* q_hi = ws + o; o += CNT;
    ushort* q_lo = ws + o; o += CNT;
    ushort* k_hi = ws + o; o += CNT;
    ushort* k_lo = ws + o; o += CNT;
    ushort* v_bf = ws + o; o += CNT;
    ushort* vtb  = ws + o; o += (size_t)BHN * DH * VTSTRIDE;
    float*  att  = (float*)(ws + o);                  // MPAD*DIM floats
    // ah/al for the proj GEMM alias xh/xl (dead after qkv_mfma).

    split_hilo<<<2048, 256, 0, stream>>>(x, xh, xl, MROWS * DIM, MPAD * DIM / 4);
    split_hilo<<<1024, 256, 0, stream>>>(qkv_w, wh, wl, 2304 * DIM, 2304 * DIM / 4);
    split_hilo<<<512, 256, 0, stream>>>(proj_w, pwh, pwl, DIM * DIM, DIM * DIM / 4);

    qkv_mfma<<<dim3(49, 18), 256, 0, stream>>>(xh, xl, wh, wl,
                                               q_hi, q_lo, k_hi, k_lo, v_bf);
    transpose_v<<<dim3(49, BHN), 256, 0, stream>>>(v_bf, vtb);
    attn_mfma<<<dim3(49, BHN), 256, 0, stream>>>(q_hi, q_lo, k_hi, k_lo, vtb, att);
    conv_pe<<<BHN * (NPATCH / 4), 256, 0, stream>>>(v_bf, conv_w, conv_b, att);

    split_hilo<<<2048, 256, 0, stream>>>(att, xh, xl, MROWS * DIM, MPAD * DIM / 4);
    proj_mfma<<<dim3(49, 6), 256, 0, stream>>>(xh, xl, pwh, pwl, proj_b, out);
}